// Round 3
// baseline (2543.406 us; speedup 1.0000x reference)
//
#include <hip/hip_runtime.h>
#include <hip/hip_bf16.h>

// Problem constants (fixed by setup_inputs)
#define H    300
#define KP   320            // K padded to multiple of 32
#define BM   2048           // num molecules
#define SEG  48
#define NTOK (BM*SEG)       // 98304
#define G    900            // 3*H
#define GW   1024           // xp row width: 8*128
#define MOLW 64             // molecules per recurrent workgroup
#define CT   19             // channel tiles of 16 (304 padded channels)
#define CP   304            // padded channels per gate

typedef __attribute__((ext_vector_type(8))) short short8;
typedef __attribute__((ext_vector_type(4))) float f32x4;

__device__ __forceinline__ float bf2f(unsigned short u) {
    return __uint_as_float(((unsigned)u) << 16);
}

// ---------------- prep: weights -> padded bf16, biases -> padded f32 ----------------
// w_ih: [dir][GW=1024 rows][KP] (for xp_gemm)
// w_hh: [dir][gate][CP=304][KP]  (gate-tiled for fused gru)
__global__ void prep_weights(const float* wih_f, const float* whh_f, const float* bih_f,
                             const float* wih_b, const float* whh_b, const float* bih_b,
                             __hip_bfloat16* wih, __hip_bfloat16* whh, float* bih) {
    int idx = blockIdx.x * 256 + threadIdx.x;
    const int wih_n = 2 * GW * KP;
    const int whh_n = 2 * 3 * CP * KP;
    if (idx < wih_n) {
        int d = idx / (GW * KP);
        int r = (idx / KP) % GW;
        int k = idx % KP;
        const float* src = d ? wih_b : wih_f;
        float v = (r < G && k < H) ? src[r * H + k] : 0.f;
        wih[idx] = __float2bfloat16(v);
        return;
    }
    idx -= wih_n;
    if (idx < whh_n) {
        int d = idx / (3 * CP * KP);
        int rem = idx % (3 * CP * KP);
        int g = rem / (CP * KP);
        int cp = (rem / KP) % CP;
        int k = idx % KP;
        const float* src = d ? whh_b : whh_f;
        float v = (cp < H && k < H) ? src[(g * H + cp) * H + k] : 0.f;
        whh[idx] = __float2bfloat16(v);
        return;
    }
    idx -= whh_n;
    if (idx < 2 * GW) {
        int d = idx / GW;
        int r = idx % GW;
        const float* src = d ? bih_b : bih_f;
        bih[idx] = (r < G) ? src[r] : 0.f;
    }
}

// ---------------- prep: message = bf16(relu(x + bias)), K-padded ----------------
__global__ void prep_msg(const float* x, const float* bias, __hip_bfloat16* msg) {
    int idx = blockIdx.x * 256 + threadIdx.x;      // over NTOK*KP = 31,457,280
    if (idx >= NTOK * KP) return;
    int i = idx / KP, k = idx % KP;
    float v = 0.f;
    if (k < H) {
        v = x[i * H + k] + bias[k];
        v = v > 0.f ? v : 0.f;
    }
    msg[idx] = __float2bfloat16(v);
}

// ---------------- prep: h0 = segment_max(x) ----------------
__global__ void h0_kernel(const float* x, float* h0) {
    int m = blockIdx.x;
    for (int c = threadIdx.x; c < H; c += blockDim.x) {
        const float* base = x + (long long)m * SEG * H + c;
        float v = -INFINITY;
        for (int t = 0; t < SEG; t++) v = fmaxf(v, base[t * H]);
        h0[m * H + c] = v;
    }
}

// ---------------- xp = msg @ w_ih^T + b_ih  (bf16 MFMA, stored bf16) ----------------
__global__ __launch_bounds__(256) void xp_gemm(const __hip_bfloat16* msg, const __hip_bfloat16* wih,
                                               const float* bih, __hip_bfloat16* xp) {
    int d = blockIdx.z;
    const short* A  = (const short*)msg;
    const short* Bw = (const short*)(wih + d * GW * KP);
    const float* bi = bih + d * GW;
    __hip_bfloat16* out = xp + (long long)d * NTOK * GW;

    int lane = threadIdx.x & 63;
    int wid  = threadIdx.x >> 6;
    int l15  = lane & 15, quad = lane >> 4;
    int mbase = blockIdx.x * 128 + (wid >> 1) * 64;
    int nbase = blockIdx.y * 128 + (wid & 1) * 64;

    f32x4 acc[4][4] = {};
    for (int kc = 0; kc < KP; kc += 32) {
        int koff = kc + quad * 8;
        short8 a[4], b[4];
#pragma unroll
        for (int i = 0; i < 4; i++)
            a[i] = *(const short8*)(A + (mbase + i * 16 + l15) * KP + koff);
#pragma unroll
        for (int j = 0; j < 4; j++)
            b[j] = *(const short8*)(Bw + (nbase + j * 16 + l15) * KP + koff);
#pragma unroll
        for (int i = 0; i < 4; i++)
#pragma unroll
            for (int j = 0; j < 4; j++)
                acc[i][j] = __builtin_amdgcn_mfma_f32_16x16x32_bf16(a[i], b[j], acc[i][j], 0, 0, 0);
    }
#pragma unroll
    for (int i = 0; i < 4; i++)
#pragma unroll
        for (int j = 0; j < 4; j++) {
            int col = nbase + j * 16 + l15;
            float bv = bi[col];
#pragma unroll
            for (int r = 0; r < 4; r++) {
                int row = mbase + i * 16 + quad * 4 + r;
                out[(long long)row * GW + col] = __float2bfloat16(acc[i][j][r] + bv);
            }
        }
}

// ---------------- persistent bidirectional GRU, fused gate epilogue ----------------
// grid (BM/MOLW=32, 2), 512 threads = 8 waves. One barrier per step.
// Wave `wid` owns channel tiles {wid, wid+8, wid+16} (<19): computes acc_r/z/n for
// 4 row-blocks of 16 molecules, then applies the GRU nonlinearity in C-layout regs.
__global__ __launch_bounds__(512, 2) void gru_kernel(const __hip_bfloat16* whh_all, const float* bhh_f,
                                                     const float* bhh_b, const __hip_bfloat16* xp,
                                                     const float* h0, float* out) {
    int grp = blockIdx.x;      // 0..31
    int d   = blockIdx.y;      // direction
    const short* Ws = (const short*)(whh_all + (size_t)d * 3 * CP * KP);
    const float* bhh = d ? bhh_b : bhh_f;
    const __hip_bfloat16* xpd = xp + (size_t)d * NTOK * GW;

    int tid = threadIdx.x;
    int lane = tid & 63, wid = tid >> 6;           // wid 0..7
    int l15 = lane & 15, quad = lane >> 4;

    // double-buffered bf16 h (A-operand); stride 328 shorts (164 dwords = 4 mod 32: conflict-safe)
    __shared__ __hip_bfloat16 hBuf[2][MOLW * 328]; // 2 x 41,984 B

    int mol0 = grp * MOLW;
    int ntiles = (wid < 3) ? 3 : 2;

    // ---- init LDS: buf0 = bf16(h0) with zero pads; buf1 = zeros ----
    for (int e = tid; e < MOLW * 328; e += 512) {
        int m = e / 328, k = e % 328;
        float v = (k < H) ? h0[(size_t)(mol0 + m) * H + k] : 0.f;
        hBuf[0][e] = __float2bfloat16(v);
        hBuf[1][e] = __float2bfloat16(0.f);
    }

    // ---- init h_old in registers (C-layout ownership, stable across steps) ----
    float hold[4][3][4];
#pragma unroll
    for (int ti = 0; ti < 3; ti++) {
        if (ti < ntiles) {
            int c = (wid + ti * 8) * 16 + l15;
            bool cv = (c < H);
#pragma unroll
            for (int rb = 0; rb < 4; rb++)
#pragma unroll
                for (int r = 0; r < 4; r++)
                    hold[rb][ti][r] = cv ? h0[(size_t)(mol0 + rb * 16 + quad * 4 + r) * H + c] : 0.f;
        }
    }
    __syncthreads();

    for (int t = 0; t < SEG; t++) {
        int tt = d ? (SEG - 1 - t) : t;
        const short* hCur = (const short*)hBuf[t & 1];
        __hip_bfloat16* hNxt = hBuf[(t + 1) & 1];

#pragma unroll
        for (int ti = 0; ti < 3; ti++) {
            if (ti >= ntiles) break;
            int nt = wid + ti * 8;
            int c = nt * 16 + l15;
            bool cv = (c < H);
            int cc = cv ? c : 0;

            // ---- xp prefetch for this tile (C-layout scalar bf16 loads, 32B-coalesced) ----
            unsigned short xpr[4][4], xpz[4][4], xpn[4][4];
#pragma unroll
            for (int rb = 0; rb < 4; rb++)
#pragma unroll
                for (int r = 0; r < 4; r++) {
                    size_t tok = (size_t)(mol0 + rb * 16 + quad * 4 + r) * SEG + tt;
                    const unsigned short* xrow = (const unsigned short*)(xpd + tok * GW);
                    xpr[rb][r] = xrow[cc];
                    xpz[rb][r] = xrow[cc + 300];
                    xpn[rb][r] = xrow[cc + 600];
                }
            float bhr = 0.f, bhz = 0.f, bhn = 0.f;
            if (cv) { bhr = bhh[c]; bhz = bhh[300 + c]; bhn = bhh[600 + c]; }

            // ---- GEMM: 3 gates x 4 row-blocks, B reused across row-blocks ----
            const short* Br = Ws + (size_t)(0 * CP + nt * 16 + l15) * KP;
            const short* Bz = Ws + (size_t)(1 * CP + nt * 16 + l15) * KP;
            const short* Bn = Ws + (size_t)(2 * CP + nt * 16 + l15) * KP;
            f32x4 ar[4] = {}, az[4] = {}, an[4] = {};
#pragma unroll
            for (int k = 0; k < 10; k++) {
                int ko = k * 32 + quad * 8;
                short8 br = *(const short8*)(Br + ko);
                short8 bz = *(const short8*)(Bz + ko);
                short8 bn = *(const short8*)(Bn + ko);
#pragma unroll
                for (int rb = 0; rb < 4; rb++) {
                    short8 a = *(const short8*)(hCur + (rb * 16 + l15) * 328 + ko);
                    ar[rb] = __builtin_amdgcn_mfma_f32_16x16x32_bf16(a, br, ar[rb], 0, 0, 0);
                    az[rb] = __builtin_amdgcn_mfma_f32_16x16x32_bf16(a, bz, az[rb], 0, 0, 0);
                    an[rb] = __builtin_amdgcn_mfma_f32_16x16x32_bf16(a, bn, an[rb], 0, 0, 0);
                }
            }

            // ---- fused gate epilogue in C-layout registers ----
            if (cv) {
#pragma unroll
                for (int rb = 0; rb < 4; rb++)
#pragma unroll
                    for (int r = 0; r < 4; r++) {
                        float hr = ar[rb][r] + bhr;
                        float hz = az[rb][r] + bhz;
                        float hn = an[rb][r] + bhn;
                        float xr = bf2f(xpr[rb][r]);
                        float xz = bf2f(xpz[rb][r]);
                        float xn = bf2f(xpn[rb][r]);
                        float rg = 1.f / (1.f + __expf(-(xr + hr)));
                        float zg = 1.f / (1.f + __expf(-(xz + hz)));
                        float ni = xn + rg * hn;
                        float ng = 1.f - 2.f / (__expf(2.f * ni) + 1.f);
                        float hnew = (1.f - zg) * ng + zg * hold[rb][ti][r];
                        hold[rb][ti][r] = hnew;
                        int row = rb * 16 + quad * 4 + r;
                        size_t tok = (size_t)(mol0 + row) * SEG + tt;
                        out[tok * 600 + d * 300 + c] = hnew;
                        hNxt[row * 328 + c] = __float2bfloat16(hnew);
                    }
            }
        }
        __syncthreads();   // hNxt complete + hCur reads done -> next step
    }
}

extern "C" void kernel_launch(void* const* d_in, const int* in_sizes, int n_in,
                              void* d_out, int out_size, void* d_ws, size_t ws_size,
                              hipStream_t stream) {
    const float* x     = (const float*)d_in[0];
    const float* bias  = (const float*)d_in[4];
    const float* wih_f = (const float*)d_in[5];
    const float* whh_f = (const float*)d_in[6];
    const float* bih_f = (const float*)d_in[7];
    const float* bhh_f = (const float*)d_in[8];
    const float* wih_b = (const float*)d_in[9];
    const float* whh_b = (const float*)d_in[10];
    const float* bih_b = (const float*)d_in[11];
    const float* bhh_b = (const float*)d_in[12];
    float* out = (float*)d_out;

    char* ws = (char*)d_ws;
    __hip_bfloat16* msg = (__hip_bfloat16*)(ws);                    //  62,914,560 B
    __hip_bfloat16* wih = (__hip_bfloat16*)(ws + 62914560LL);       //   1,310,720 B
    __hip_bfloat16* whh = (__hip_bfloat16*)(ws + 64225280LL);       //   1,167,360 B (gate-tiled)
    float*          bih = (float*)         (ws + 65392640LL);       //       8,192 B
    float*          h0  = (float*)         (ws + 65400832LL);       //   2,457,600 B
    __hip_bfloat16* xp  = (__hip_bfloat16*)(ws + 67858432LL);       // 402,653,184 B

    hipLaunchKernelGGL(prep_weights, dim3((2*GW*KP + 2*3*CP*KP + 2*GW + 255) / 256), dim3(256), 0, stream,
                       wih_f, whh_f, bih_f, wih_b, whh_b, bih_b, wih, whh, bih);
    hipLaunchKernelGGL(prep_msg, dim3((NTOK * KP + 255) / 256), dim3(256), 0, stream, x, bias, msg);
    hipLaunchKernelGGL(h0_kernel, dim3(BM), dim3(256), 0, stream, x, h0);
    hipLaunchKernelGGL(xp_gemm, dim3(NTOK / 128, GW / 128, 2), dim3(256), 0, stream, msg, wih, bih, xp);
    hipLaunchKernelGGL(gru_kernel, dim3(BM / MOLW, 2), dim3(512), 0, stream, whh, bhh_f, bhh_b, xp, h0, out);
}